// Round 7
// baseline (11199.380 us; speedup 1.0000x reference)
//
#include <hip/hip_runtime.h>
#include <stdint.h>

#define H 128
#define G 512   // 4*H
#define T 2048
#define B 256
#define NF 5

__device__ __forceinline__ float sigmoidf_(float x) {
  return 1.0f / (1.0f + __expf(-x));
}
__device__ __forceinline__ float tanhf_(float x) {
  float e = __expf(2.0f * x);
  return 1.0f - 2.0f / (e + 1.0f);
}

// zero the persistent state block (4*B*H floats: h0,c0,h1s,c1s)
__global__ void init_state(float* __restrict__ st) {
  int i = blockIdx.x * blockDim.x + threadIdx.x;
  if (i < 4 * B * H) st[i] = 0.0f;
}

// ---- Layer 0 chunk: K=5 input fused + K=128 recurrent. Proven 0.66us/step. ----
__global__ __launch_bounds__(512, 2)
void lstm0(const float* __restrict__ x, const float* __restrict__ Wih,
           const float* __restrict__ Whh, const float* __restrict__ bih,
           const float* __restrict__ bhh, float* __restrict__ h0st,
           float* __restrict__ c0st, float* __restrict__ h1buf,
           int s0, int CH)
{
  const int b = blockIdx.x;
  const int t = threadIdx.x;      // gate row 0..511
  __shared__ float4 h4[H/4];
  __shared__ float gates[G];
  float* hs = (float*)h4;

  float4 w[H/4];                  // 128 VGPRs of W_hh row t — fits
  #pragma unroll
  for (int i = 0; i < H/4; ++i) w[i] = ((const float4*)Whh)[t*(H/4) + i];
  const float wi0 = Wih[t*NF+0], wi1 = Wih[t*NF+1], wi2 = Wih[t*NF+2],
              wi3 = Wih[t*NF+3], wi4 = Wih[t*NF+4];
  const float bias = bih[t] + bhh[t];
  float c = 0.0f;
  if (t < H) { hs[t] = h0st[b*H + t]; c = c0st[b*H + t]; }
  __syncthreads();

  const float* xb  = x + ((size_t)b * T + s0) * NF;
  float*       h1b = h1buf + (size_t)b * CH * H;
  for (int s = 0; s < CH; ++s) {
    float a0 = bias + wi0*xb[s*NF+0] + wi1*xb[s*NF+1] + wi2*xb[s*NF+2]
                    + wi3*xb[s*NF+3] + wi4*xb[s*NF+4];
    float a1 = 0.f, a2 = 0.f, a3 = 0.f;
    #pragma unroll
    for (int i = 0; i < H/4; ++i) {
      float4 hv = h4[i];             // broadcast ds_read_b128
      a0 += w[i].x * hv.x;
      a1 += w[i].y * hv.y;
      a2 += w[i].z * hv.z;
      a3 += w[i].w * hv.w;
    }
    gates[t] = (a0 + a1) + (a2 + a3);
    __syncthreads();
    if (t < H) {
      float gi = sigmoidf_(gates[t]);
      float gf = sigmoidf_(gates[H + t]);
      float gg = tanhf_  (gates[2*H + t]);
      float go = sigmoidf_(gates[3*H + t]);
      c = gf * c + gi * gg;
      float h = go * tanhf_(c);
      hs[t] = h;
      h1b[(size_t)s*H + t] = h;      // coalesced 512B store
    }
    __syncthreads();
  }
  if (t < H) { h0st[b*H + t] = hs[t]; c0st[b*H + t] = c; }
}

// ---- xg GEMM: C[rows][512] = A[rows][128] @ W[512][128]^T (fp32, reg-tiled) ----
// TM=128 rows x TN=128 gates per block, 256 threads, 8x8 micro-tile, K=128 whole.
#define TMg 128
#define TNg 128
#define PAD 129   // 8-row stride = 1032 words = 8 mod 32 banks -> spread
__global__ __launch_bounds__(256, 1)
void xg_gemm(const float* __restrict__ A, const float* __restrict__ W,
             float* __restrict__ C)
{
  __shared__ float As[TMg][PAD];
  __shared__ float Ws[TNg][PAD];
  const int r0 = blockIdx.x * TMg;
  const int g0 = blockIdx.y * TNg;
  const int tid = threadIdx.x;

  // stage A-tile and W-tile (each 128 rows x 32 float4)
  for (int i = tid; i < TMg * 32; i += 256) {
    int r = i >> 5, c4 = i & 31;
    float4 v = ((const float4*)(A + (size_t)(r0 + r) * H))[c4];
    As[r][c4*4+0] = v.x; As[r][c4*4+1] = v.y;
    As[r][c4*4+2] = v.z; As[r][c4*4+3] = v.w;
    float4 u = ((const float4*)(W + (size_t)(g0 + r) * H))[c4];
    Ws[r][c4*4+0] = u.x; Ws[r][c4*4+1] = u.y;
    Ws[r][c4*4+2] = u.z; Ws[r][c4*4+3] = u.w;
  }
  __syncthreads();

  const int rg = tid >> 4;          // 0..15 row group
  const int gg = tid & 15;          // 0..15 gate group
  float acc[8][8];
  #pragma unroll
  for (int i = 0; i < 8; ++i)
    #pragma unroll
    for (int j = 0; j < 8; ++j) acc[i][j] = 0.0f;

  for (int k = 0; k < H; ++k) {
    float a[8], w[8];
    #pragma unroll
    for (int i = 0; i < 8; ++i) a[i] = As[rg*8 + i][k];
    #pragma unroll
    for (int j = 0; j < 8; ++j) w[j] = Ws[gg*8 + j][k];
    #pragma unroll
    for (int i = 0; i < 8; ++i)
      #pragma unroll
      for (int j = 0; j < 8; ++j) acc[i][j] += a[i] * w[j];
  }

  #pragma unroll
  for (int i = 0; i < 8; ++i) {
    float* crow = C + (size_t)(r0 + rg*8 + i) * G + g0 + gg*8;
    #pragma unroll
    for (int j4 = 0; j4 < 2; ++j4) {
      float4 v = make_float4(acc[i][j4*4+0], acc[i][j4*4+1],
                             acc[i][j4*4+2], acc[i][j4*4+3]);
      ((float4*)crow)[j4] = v;
    }
  }
}

// ---- Layer 1 slim: gates = xg[s] + h @ W_hh^T (K=128 only, 128-VGPR weights) ----
__global__ __launch_bounds__(512, 2)
void lstm1s(const float* __restrict__ xg, const float* __restrict__ Whh,
            const float* __restrict__ bih, const float* __restrict__ bhh,
            float* __restrict__ h1st, float* __restrict__ c1st,
            float* __restrict__ h2last, int s0, int CH)
{
  const int b = blockIdx.x;
  const int t = threadIdx.x;
  __shared__ float4 h4[H/4];
  __shared__ float gates[G];
  float* hs = (float*)h4;

  float4 w[H/4];                  // 128 VGPRs of W_hh row t
  #pragma unroll
  for (int i = 0; i < H/4; ++i) w[i] = ((const float4*)Whh)[t*(H/4) + i];
  const float bias = bih[t] + bhh[t];
  float c = 0.0f;
  if (t < H) { hs[t] = h1st[b*H + t]; c = c1st[b*H + t]; }
  __syncthreads();

  const float* xgb = xg + (size_t)b * CH * G;
  float xv = xgb[t];                               // prefetch step 0
  for (int s = 0; s < CH; ++s) {
    float a0 = bias + xv;
    float a1 = 0.f, a2 = 0.f, a3 = 0.f;
    #pragma unroll
    for (int i = 0; i < H/4; ++i) {
      float4 hv = h4[i];             // broadcast ds_read_b128
      a0 += w[i].x * hv.x;
      a1 += w[i].y * hv.y;
      a2 += w[i].z * hv.z;
      a3 += w[i].w * hv.w;
    }
    float xv_n = (s + 1 < CH) ? xgb[(size_t)(s+1)*G + t] : 0.0f;  // prefetch s+1
    gates[t] = (a0 + a1) + (a2 + a3);
    __syncthreads();
    if (t < H) {
      float gi = sigmoidf_(gates[t]);
      float gf = sigmoidf_(gates[H + t]);
      float gg = tanhf_  (gates[2*H + t]);
      float go = sigmoidf_(gates[3*H + t]);
      c = gf * c + gi * gg;
      float h = go * tanhf_(c);
      hs[t] = h;
      if (s0 + s == T - 1) h2last[(size_t)b*H + t] = h;
    }
    __syncthreads();
    xv = xv_n;
  }
  if (t < H) { h1st[b*H + t] = hs[t]; c1st[b*H + t] = c; }
}

// ---- Output: JAX partitionable-threefry dropout mask + 7x128 GEMV ----
__device__ __forceinline__ void threefry2x32_(uint32_t x0, uint32_t x1,
                                              uint32_t* o0, uint32_t* o1)
{
  const uint32_t k0 = 0u, k1 = 42u;
  const uint32_t k2 = k0 ^ k1 ^ 0x1BD11BDAu;
  x0 += k0; x1 += k1;
#define RR_(x, r) (((x) << (r)) | ((x) >> (32 - (r))))
#define RND_(r) { x0 += x1; x1 = RR_(x1, r); x1 ^= x0; }
  RND_(13) RND_(15) RND_(26) RND_(6)   x0 += k1; x1 += k2 + 1u;
  RND_(17) RND_(29) RND_(16) RND_(24)  x0 += k2; x1 += k0 + 2u;
  RND_(13) RND_(15) RND_(26) RND_(6)   x0 += k0; x1 += k1 + 3u;
  RND_(17) RND_(29) RND_(16) RND_(24)  x0 += k1; x1 += k2 + 4u;
  RND_(13) RND_(15) RND_(26) RND_(6)   x0 += k2; x1 += k0 + 5u;
#undef RND_
#undef RR_
  *o0 = x0; *o1 = x1;
}

__global__ void out_kernel(const float* __restrict__ h2last,
                           const float* __restrict__ Wout,
                           const float* __restrict__ bout,
                           float* __restrict__ out)
{
  const int b = blockIdx.x;
  const int j = threadIdx.x;   // 0..127
  __shared__ float vals[H];
  uint32_t m = (uint32_t)(b * H + j);
  // jax_threefry_partitionable: bits = o0 ^ o1 of threefry(key,(0,m))  [verified R5]
  uint32_t o0, o1;
  threefry2x32_(0u, m, &o0, &o1);
  uint32_t bits = o0 ^ o1;
  float u = __uint_as_float(0x3f800000u | (bits >> 9)) - 1.0f;  // uniform [0,1)
  float v = (u < 0.7f) ? (h2last[m] / 0.7f) : 0.0f;
  vals[j] = v;
  __syncthreads();
  if (j < 7) {
    float a = bout[j];
    #pragma unroll
    for (int k = 0; k < H; ++k) a += vals[k] * Wout[j*H + k];
    out[b*7 + j] = a;
  }
}

extern "C" void kernel_launch(void* const* d_in, const int* in_sizes, int n_in,
                              void* d_out, int out_size, void* d_ws, size_t ws_size,
                              hipStream_t stream) {
  const float* x    = (const float*)d_in[0];
  const float* Wih0 = (const float*)d_in[1];
  const float* Whh0 = (const float*)d_in[2];
  const float* bih0 = (const float*)d_in[3];
  const float* bhh0 = (const float*)d_in[4];
  const float* Wih1 = (const float*)d_in[5];
  const float* Whh1 = (const float*)d_in[6];
  const float* bih1 = (const float*)d_in[7];
  const float* bhh1 = (const float*)d_in[8];
  const float* Wout = (const float*)d_in[9];
  const float* bout = (const float*)d_in[10];

  // ws layout: [h0 | c0 | h1s | c1s | h2last] (5*B*H f32) then h1buf, xgbuf
  float* st    = (float*)d_ws;
  float* h0s   = st;
  float* c0s   = st + 1*B*H;
  float* h1s   = st + 2*B*H;
  float* c1s   = st + 3*B*H;
  float* h2l   = st + 4*B*H;
  float* bufs  = st + 5*B*H;

  const size_t state_bytes = (size_t)5 * B * H * sizeof(float);
  // per step: h1 (B*H) + xg (B*G) floats
  const size_t per_step = (size_t)B * (H + G) * sizeof(float);   // 640 KB
  int CH = 1;
  if (ws_size > state_bytes) {
    size_t m = (ws_size - state_bytes) / per_step;
    while (CH * 2 <= (int)m && CH * 2 <= T) CH *= 2;             // pow2 divisor of T
  }
  float* h1buf = bufs;                          // B*CH*H
  float* xgbuf = bufs + (size_t)B * CH * H;     // B*CH*G
  float* out   = (float*)d_out;

  init_state<<<(4*B*H + 255)/256, 256, 0, stream>>>(st);
  dim3 ggrid((B * CH) / TMg, G / TNg);
  for (int s0 = 0; s0 < T; s0 += CH) {
    lstm0<<<B, 512, 0, stream>>>(x, Wih0, Whh0, bih0, bhh0, h0s, c0s, h1buf, s0, CH);
    xg_gemm<<<ggrid, 256, 0, stream>>>(h1buf, Wih1, xgbuf);
    lstm1s<<<B, 512, 0, stream>>>(xgbuf, Whh1, bih1, bhh1, h1s, c1s, h2l, s0, CH);
  }
  out_kernel<<<B, H, 0, stream>>>(h2l, Wout, bout, out);
}

// Round 14
// 6466.086 us; speedup vs baseline: 1.7320x; 1.7320x over previous
//
#include <hip/hip_runtime.h>
#include <stdint.h>

#define H 128
#define G 512   // 4*H
#define T 2048
#define B 256
#define NF 5

__device__ __forceinline__ float sigmoidf_(float x) {
  return 1.0f / (1.0f + __expf(-x));
}
__device__ __forceinline__ float tanhf_(float x) {
  float e = __expf(2.0f * x);
  return 1.0f - 2.0f / (e + 1.0f);
}

// zero the persistent state block (4*B*H floats: h0,c0,h1s,c1s)
__global__ void init_state(float* __restrict__ st) {
  int i = blockIdx.x * blockDim.x + threadIdx.x;
  if (i < 4 * B * H) st[i] = 0.0f;
}

// ---- Layer 0, split-K: 1024 thr, thread (g,half) holds 64 W_hh weights ----
__global__ __launch_bounds__(1024, 4)
void lstm0(const float* __restrict__ x, const float* __restrict__ Wih,
           const float* __restrict__ Whh, const float* __restrict__ bih,
           const float* __restrict__ bhh, float* __restrict__ h0st,
           float* __restrict__ c0st, float* __restrict__ h1buf,
           int s0, int CH)
{
  const int b    = blockIdx.x;
  const int tid  = threadIdx.x;
  const int g    = tid & 511;     // gate row
  const int half = tid >> 9;      // K-half: 0 -> k[0,64), 1 -> k[64,128)
  __shared__ float4 hs4[H/4];     // h[128]
  __shared__ float  part[2][G];   // partial dot products, 4KB
  float* hsm = (float*)hs4;

  float4 w[16];                   // 64 VGPRs — fits, no spill
  #pragma unroll
  for (int i = 0; i < 16; ++i)
    w[i] = ((const float4*)(Whh + (size_t)g * H + half * 64))[i];
  float wi0 = 0.f, wi1 = 0.f, wi2 = 0.f, wi3 = 0.f, wi4 = 0.f, bias = 0.f;
  if (half == 0) {
    wi0 = Wih[g*NF+0]; wi1 = Wih[g*NF+1]; wi2 = Wih[g*NF+2];
    wi3 = Wih[g*NF+3]; wi4 = Wih[g*NF+4];
    bias = bih[g] + bhh[g];
  }
  float c = 0.0f;
  if (tid < H) { hsm[tid] = h0st[b*H + tid]; c = c0st[b*H + tid]; }
  __syncthreads();

  const float* xb  = x + ((size_t)b * T + s0) * NF;
  float*       h1b = h1buf + (size_t)b * CH * H;
  for (int s = 0; s < CH; ++s) {
    float a0 = 0.f, a1 = 0.f, a2 = 0.f, a3 = 0.f;
    if (half == 0)
      a0 = bias + wi0*xb[s*NF+0] + wi1*xb[s*NF+1] + wi2*xb[s*NF+2]
                + wi3*xb[s*NF+3] + wi4*xb[s*NF+4];   // wave-uniform scalar loads
    #pragma unroll
    for (int i = 0; i < 16; ++i) {
      float4 hv = hs4[half*16 + i];    // wave-uniform broadcast ds_read_b128
      a0 += w[i].x * hv.x; a1 += w[i].y * hv.y;
      a2 += w[i].z * hv.z; a3 += w[i].w * hv.w;
    }
    part[half][g] = (a0 + a1) + (a2 + a3);   // stride-1, conflict-free
    __syncthreads();
    if (tid < H) {
      float gi = sigmoidf_(part[0][tid]       + part[1][tid]);
      float gf = sigmoidf_(part[0][H+tid]     + part[1][H+tid]);
      float gg = tanhf_  (part[0][2*H+tid]    + part[1][2*H+tid]);
      float go = sigmoidf_(part[0][3*H+tid]   + part[1][3*H+tid]);
      c = gf * c + gi * gg;
      float h = go * tanhf_(c);
      hsm[tid] = h;
      h1b[(size_t)s*H + tid] = h;      // coalesced 512B store
    }
    __syncthreads();
  }
  if (tid < H) { h0st[b*H + tid] = hsm[tid]; c0st[b*H + tid] = c; }
}

// ---- xg GEMM: C[rows][512] = A[rows][128] @ W[512][128]^T (fp32, reg-tiled) ----
#define TMg 128
#define TNg 128
#define PAD 129
__global__ __launch_bounds__(256, 1)
void xg_gemm(const float* __restrict__ A, const float* __restrict__ W,
             float* __restrict__ C)
{
  __shared__ float As[TMg][PAD];
  __shared__ float Ws[TNg][PAD];
  const int r0 = blockIdx.x * TMg;
  const int g0 = blockIdx.y * TNg;
  const int tid = threadIdx.x;

  for (int i = tid; i < TMg * 32; i += 256) {
    int r = i >> 5, c4 = i & 31;
    float4 v = ((const float4*)(A + (size_t)(r0 + r) * H))[c4];
    As[r][c4*4+0] = v.x; As[r][c4*4+1] = v.y;
    As[r][c4*4+2] = v.z; As[r][c4*4+3] = v.w;
    float4 u = ((const float4*)(W + (size_t)(g0 + r) * H))[c4];
    Ws[r][c4*4+0] = u.x; Ws[r][c4*4+1] = u.y;
    Ws[r][c4*4+2] = u.z; Ws[r][c4*4+3] = u.w;
  }
  __syncthreads();

  const int rg = tid >> 4;
  const int gg = tid & 15;
  float acc[8][8];
  #pragma unroll
  for (int i = 0; i < 8; ++i)
    #pragma unroll
    for (int j = 0; j < 8; ++j) acc[i][j] = 0.0f;

  for (int k = 0; k < H; ++k) {
    float a[8], w[8];
    #pragma unroll
    for (int i = 0; i < 8; ++i) a[i] = As[rg*8 + i][k];
    #pragma unroll
    for (int j = 0; j < 8; ++j) w[j] = Ws[gg*8 + j][k];
    #pragma unroll
    for (int i = 0; i < 8; ++i)
      #pragma unroll
      for (int j = 0; j < 8; ++j) acc[i][j] += a[i] * w[j];
  }

  #pragma unroll
  for (int i = 0; i < 8; ++i) {
    float* crow = C + (size_t)(r0 + rg*8 + i) * G + g0 + gg*8;
    #pragma unroll
    for (int j4 = 0; j4 < 2; ++j4) {
      float4 v = make_float4(acc[i][j4*4+0], acc[i][j4*4+1],
                             acc[i][j4*4+2], acc[i][j4*4+3]);
      ((float4*)crow)[j4] = v;
    }
  }
}

// ---- Layer 1, split-K slim: gates = xg[s] + h @ W_hh^T ----
__global__ __launch_bounds__(1024, 4)
void lstm1s(const float* __restrict__ xg, const float* __restrict__ Whh,
            const float* __restrict__ bih, const float* __restrict__ bhh,
            float* __restrict__ h1st, float* __restrict__ c1st,
            float* __restrict__ h2last, int s0, int CH)
{
  const int b    = blockIdx.x;
  const int tid  = threadIdx.x;
  const int g    = tid & 511;
  const int half = tid >> 9;
  __shared__ float4 hs4[H/4];
  __shared__ float  part[2][G];
  float* hsm = (float*)hs4;

  float4 w[16];                   // 64 VGPRs — fits, no spill
  #pragma unroll
  for (int i = 0; i < 16; ++i)
    w[i] = ((const float4*)(Whh + (size_t)g * H + half * 64))[i];
  float bias = 0.f;
  if (half == 0) bias = bih[g] + bhh[g];
  float c = 0.0f;
  if (tid < H) { hsm[tid] = h1st[b*H + tid]; c = c1st[b*H + tid]; }
  __syncthreads();

  const float* xgb = xg + (size_t)b * CH * G;
  float xv = (half == 0) ? xgb[g] : 0.f;       // prefetch step 0
  for (int s = 0; s < CH; ++s) {
    // issue next-step prefetch early so HBM/L3 latency hides under FMAs+barrier
    float xv_n = (half == 0 && s + 1 < CH) ? xgb[(size_t)(s+1)*G + g] : 0.f;
    float a0 = (half == 0) ? (bias + xv) : 0.f;
    float a1 = 0.f, a2 = 0.f, a3 = 0.f;
    #pragma unroll
    for (int i = 0; i < 16; ++i) {
      float4 hv = hs4[half*16 + i];    // broadcast
      a0 += w[i].x * hv.x; a1 += w[i].y * hv.y;
      a2 += w[i].z * hv.z; a3 += w[i].w * hv.w;
    }
    part[half][g] = (a0 + a1) + (a2 + a3);
    __syncthreads();
    if (tid < H) {
      float gi = sigmoidf_(part[0][tid]     + part[1][tid]);
      float gf = sigmoidf_(part[0][H+tid]   + part[1][H+tid]);
      float gg = tanhf_  (part[0][2*H+tid]  + part[1][2*H+tid]);
      float go = sigmoidf_(part[0][3*H+tid] + part[1][3*H+tid]);
      c = gf * c + gi * gg;
      float h = go * tanhf_(c);
      hsm[tid] = h;
      if (s0 + s == T - 1) h2last[(size_t)b*H + tid] = h;
    }
    __syncthreads();
    xv = xv_n;
  }
  if (tid < H) { h1st[b*H + tid] = hsm[tid]; c1st[b*H + tid] = c; }
}

// ---- Output: JAX partitionable-threefry dropout mask + 7x128 GEMV ----
__device__ __forceinline__ void threefry2x32_(uint32_t x0, uint32_t x1,
                                              uint32_t* o0, uint32_t* o1)
{
  const uint32_t k0 = 0u, k1 = 42u;
  const uint32_t k2 = k0 ^ k1 ^ 0x1BD11BDAu;
  x0 += k0; x1 += k1;
#define RR_(x, r) (((x) << (r)) | ((x) >> (32 - (r))))
#define RND_(r) { x0 += x1; x1 = RR_(x1, r); x1 ^= x0; }
  RND_(13) RND_(15) RND_(26) RND_(6)   x0 += k1; x1 += k2 + 1u;
  RND_(17) RND_(29) RND_(16) RND_(24)  x0 += k2; x1 += k0 + 2u;
  RND_(13) RND_(15) RND_(26) RND_(6)   x0 += k0; x1 += k1 + 3u;
  RND_(17) RND_(29) RND_(16) RND_(24)  x0 += k1; x1 += k2 + 4u;
  RND_(13) RND_(15) RND_(26) RND_(6)   x0 += k2; x1 += k0 + 5u;
#undef RND_
#undef RR_
  *o0 = x0; *o1 = x1;
}

__global__ void out_kernel(const float* __restrict__ h2last,
                           const float* __restrict__ Wout,
                           const float* __restrict__ bout,
                           float* __restrict__ out)
{
  const int b = blockIdx.x;
  const int j = threadIdx.x;   // 0..127
  __shared__ float vals[H];
  uint32_t m = (uint32_t)(b * H + j);
  // jax_threefry_partitionable: bits = o0 ^ o1 of threefry(key,(0,m))  [verified R5]
  uint32_t o0, o1;
  threefry2x32_(0u, m, &o0, &o1);
  uint32_t bits = o0 ^ o1;
  float u = __uint_as_float(0x3f800000u | (bits >> 9)) - 1.0f;  // uniform [0,1)
  float v = (u < 0.7f) ? (h2last[m] / 0.7f) : 0.0f;
  vals[j] = v;
  __syncthreads();
  if (j < 7) {
    float a = bout[j];
    #pragma unroll
    for (int k = 0; k < H; ++k) a += vals[k] * Wout[j*H + k];
    out[b*7 + j] = a;
  }
}

extern "C" void kernel_launch(void* const* d_in, const int* in_sizes, int n_in,
                              void* d_out, int out_size, void* d_ws, size_t ws_size,
                              hipStream_t stream) {
  const float* x    = (const float*)d_in[0];
  const float* Wih0 = (const float*)d_in[1];
  const float* Whh0 = (const float*)d_in[2];
  const float* bih0 = (const float*)d_in[3];
  const float* bhh0 = (const float*)d_in[4];
  const float* Wih1 = (const float*)d_in[5];
  const float* Whh1 = (const float*)d_in[6];
  const float* bih1 = (const float*)d_in[7];
  const float* bhh1 = (const float*)d_in[8];
  const float* Wout = (const float*)d_in[9];
  const float* bout = (const float*)d_in[10];

  // ws layout: [h0 | c0 | h1s | c1s | h2last] (5*B*H f32) then h1buf, xgbuf
  float* st    = (float*)d_ws;
  float* h0s   = st;
  float* c0s   = st + 1*B*H;
  float* h1s   = st + 2*B*H;
  float* c1s   = st + 3*B*H;
  float* h2l   = st + 4*B*H;
  float* bufs  = st + 5*B*H;

  const size_t state_bytes = (size_t)5 * B * H * sizeof(float);
  // per step: h1 (B*H) + xg (B*G) floats
  const size_t per_step = (size_t)B * (H + G) * sizeof(float);   // 640 KB
  int CH = 1;
  if (ws_size > state_bytes) {
    size_t m = (ws_size - state_bytes) / per_step;
    while (CH * 2 <= (int)m && CH * 2 <= T) CH *= 2;             // pow2 divisor of T
  }
  float* h1buf = bufs;                          // B*CH*H
  float* xgbuf = bufs + (size_t)B * CH * H;     // B*CH*G
  float* out   = (float*)d_out;

  init_state<<<(4*B*H + 255)/256, 256, 0, stream>>>(st);
  dim3 ggrid((B * CH) / TMg, G / TNg);
  for (int s0 = 0; s0 < T; s0 += CH) {
    lstm0<<<B, 1024, 0, stream>>>(x, Wih0, Whh0, bih0, bhh0, h0s, c0s, h1buf, s0, CH);
    xg_gemm<<<ggrid, 256, 0, stream>>>(h1buf, Wih1, xgbuf);
    lstm1s<<<B, 1024, 0, stream>>>(xgbuf, Whh1, bih1, bhh1, h1s, c1s, h2l, s0, CH);
  }
  out_kernel<<<B, H, 0, stream>>>(h2l, Wout, bout, out);
}